// Round 11
// baseline (3371.219 us; speedup 1.0000x reference)
//
#include <hip/hip_runtime.h>

#define B_ 128
#define T_ 2048
#define H_ 128
#define IN_ 6
#define GRP_ 8            // steps per inner group
#define NGRP_ (T_ / GRP_) // 256
#define CHUNK_ 32         // steps per flag publish
#define FLAG_STRIDE_ 64   // uints between flags (256B)
#define HS_ 144           // LDS row stride in shorts
#define NBLK_ 268         // 256 + 12: wrap-pairing of 24 roles, 2 WGs/CU

typedef _Float16 f16x8 __attribute__((ext_vector_type(8)));
typedef float    f32x4 __attribute__((ext_vector_type(4)));

__device__ __forceinline__ unsigned short f2h_u(float f) {
  union { _Float16 h; unsigned short u; } v; v.h = (_Float16)f; return v.u;
}
__device__ __forceinline__ unsigned int pack2(float a, float b) {
  return (unsigned int)f2h_u(a) | ((unsigned int)f2h_u(b) << 16);
}
// fast sigmoid/tanh: v_exp + v_rcp (no IEEE divide sequence).
__device__ __forceinline__ float sigf_(float x) {
  return __builtin_amdgcn_rcpf(1.0f + __expf(-x));
}
__device__ __forceinline__ float tanhf_(float x) {
  return 2.0f * __builtin_amdgcn_rcpf(1.0f + __expf(-2.0f * x)) - 1.0f;
}
__device__ __forceinline__ f16x8 load_w8(const float* __restrict__ p) {
  f16x8 r;
#pragma unroll
  for (int i = 0; i < 8; ++i) r[i] = (_Float16)p[i];
  return r;
}

__global__ void init_flags(unsigned int* flags) {
  flags[blockIdx.x * 256 + threadIdx.x] = 0u;
}

// ---------------------------------------------------------------------------
// Persistent pipelined 3-layer LSTM; 24 active roles (layer, batch-group).
// Roles at blockIdx 0-11 and 256-267: with round-robin block->CU placement the
// wrapped blocks land as SECOND workgroups on the same CUs, giving 4 waves/SIMD
// (VGPR=128 and LDS 2x47.5KB both permit 2 WGs/CU at launch_bounds(512,2) --
// R9's regression was the (512,4) VGPR=64 spill, not the pairing).
// Pairs: (L0,bg)+(L1,bg) same CU (balanced issue + same-L2 handoff); L2+L2.
// ---------------------------------------------------------------------------
__global__ __launch_bounds__(512, 2)
void lstm_pipe(const float* __restrict__ x,
               const float* __restrict__ Wih0, const float* __restrict__ Whh0,
               const float* __restrict__ bih0, const float* __restrict__ bhh0,
               const float* __restrict__ Wih1, const float* __restrict__ Whh1,
               const float* __restrict__ bih1, const float* __restrict__ bhh1,
               const float* __restrict__ Wih2, const float* __restrict__ Whh2,
               const float* __restrict__ bih2, const float* __restrict__ bhh2,
               unsigned short* __restrict__ region,
               unsigned int* __restrict__ state_h,
               unsigned int* __restrict__ flags)
{
  const int bid = blockIdx.x;
  int role;
  if      (bid < 8)                  role = 0 * 8 + bid;             // L0 bg 0..7
  else if (bid < 12)                 role = 2 * 8 + (bid - 8);       // L2 bg 0..3
  else if (bid >= 256 && bid < 264)  role = 1 * 8 + (bid - 256);     // L1 bg 0..7
  else if (bid >= 264 && bid < 268)  role = 2 * 8 + 4 + (bid - 264); // L2 bg 4..7
  else return;

  const int layer = role >> 3;
  const int bg    = role & 7;
  const int tid   = threadIdx.x;
  const int lane  = tid & 63;
  const int wv    = tid >> 6;       // 0..7: owns units [16wv,16wv+16)
  const int n16   = lane & 15;      // batch within group
  const int quad  = lane >> 4;

  const float* Wih = (layer == 0) ? Wih0 : ((layer == 1) ? Wih1 : Wih2);
  const float* Whh = (layer == 0) ? Whh0 : ((layer == 1) ? Whh1 : Whh2);
  const float* bih = (layer == 0) ? bih0 : ((layer == 1) ? bih1 : bih2);
  const float* bhh = (layer == 0) ? bhh0 : ((layer == 1) ? bhh1 : bhh2);

  __shared__ unsigned short hstate[2][16][HS_];
  __shared__ unsigned short hbufL[GRP_][16][HS_];
  __shared__ unsigned short xbuf[GRP_][16][8];
  __shared__ int s_have;

  // ---- weights -> register A-frags
  f16x8 whh[4][4];
#pragma unroll
  for (int j = 0; j < 4; ++j)
#pragma unroll
    for (int kc = 0; kc < 4; ++kc)
      whh[j][kc] = load_w8(Whh + (size_t)(j * 128 + 16 * wv + n16) * H_ + kc * 32 + quad * 8);

  f16x8 wih[4][4];
  if (layer) {
#pragma unroll
    for (int j = 0; j < 4; ++j)
#pragma unroll
      for (int kc = 0; kc < 4; ++kc)
        wih[j][kc] = load_w8(Wih + (size_t)(j * 128 + 16 * wv + n16) * H_ + kc * 32 + quad * 8);
  }
  f16x8 wx[4];
#pragma unroll
  for (int j = 0; j < 4; ++j)
#pragma unroll
    for (int i = 0; i < 8; ++i) wx[j][i] = (_Float16)0.f;
  if (!layer && quad == 0) {
#pragma unroll
    for (int j = 0; j < 4; ++j) {
      const float* p = Wih + (size_t)(j * 128 + 16 * wv + n16) * IN_;
#pragma unroll
      for (int i = 0; i < IN_; ++i) wx[j][i] = (_Float16)p[i];
    }
  }

  // bias folded into whh-chain C-init
  f32x4 bias4[4];
#pragma unroll
  for (int j = 0; j < 4; ++j)
#pragma unroll
    for (int r = 0; r < 4; ++r) {
      int row = j * 128 + 16 * wv + quad * 4 + r;
      bias4[j][r] = bih[row] + bhh[row];
    }

  f32x4 c4 = {0.f, 0.f, 0.f, 0.f};
  const f32x4 z4 = {0.f, 0.f, 0.f, 0.f};

  for (int i = tid; i < (2 * 16 * HS_) / 2; i += 512) ((unsigned int*)hstate)[i] = 0u;

  unsigned int* flag_in  = (layer > 0) ? &flags[((layer - 1) * 8 + bg) * FLAG_STRIDE_] : nullptr;
  unsigned int* flag_out = (layer < 2) ? &flags[(layer * 8 + bg) * FLAG_STRIDE_] : nullptr;

  uint4 sreg[4];
  uint4 xreg = {0u, 0u, 0u, 0u};
  const int sn_h = tid >> 5, st_h = (tid >> 2) & 7, sq_h = tid & 3;
  const int sn_x = tid >> 3, st_x = tid & 7;

  int have = 0;

  // consumer wait: relaxed poll, acquire finalize (one L2-inv per chunk)
#define WAIT_FOR(need_)                                                          \
  do {                                                                           \
    if (have < (need_)) {                                                        \
      if (tid == 0) {                                                            \
        int v = (int)__hip_atomic_load(flag_in, __ATOMIC_RELAXED,                \
                                       __HIP_MEMORY_SCOPE_AGENT);                \
        while (v < (need_)) {                                                    \
          __builtin_amdgcn_s_sleep(4);                                           \
          v = (int)__hip_atomic_load(flag_in, __ATOMIC_RELAXED,                  \
                                     __HIP_MEMORY_SCOPE_AGENT);                  \
        }                                                                        \
        (void)__hip_atomic_load(flag_in, __ATOMIC_ACQUIRE,                       \
                                __HIP_MEMORY_SCOPE_AGENT);                       \
        s_have = v;                                                              \
      }                                                                          \
      __syncthreads();                                                           \
      have = s_have;                                                             \
    }                                                                            \
  } while (0)

  // ---- pre-stage group 0
  if (layer) WAIT_FOR(1);
  __syncthreads();
  if (layer) {
    const uint4* gp = (const uint4*)(region + ((size_t)(bg * 16 + sn_h) * T_ + st_h) * H_ + sq_h * 32);
#pragma unroll
    for (int i = 0; i < 4; ++i) sreg[i] = gp[i];
    uint4* lp = (uint4*)&hbufL[st_h][sn_h][sq_h * 32];
#pragma unroll
    for (int i = 0; i < 4; ++i) lp[i] = sreg[i];
  } else if (tid < 128) {
    const float* xp = x + ((size_t)(bg * 16 + sn_x) * T_ + st_x) * IN_;
    xreg.x = pack2(xp[0], xp[1]); xreg.y = pack2(xp[2], xp[3]);
    xreg.z = pack2(xp[4], xp[5]); xreg.w = 0u;
    *(uint4*)&xbuf[st_x][sn_x][0] = xreg;
  }
  __syncthreads();

  unsigned int d0[GRP_], d1[GRP_];

  for (int g = 0; g < NGRP_; ++g) {
    int gs = (g + 1 < NGRP_) ? (g + 1) : g;

    if (layer) WAIT_FOR((8 * gs + 7) / CHUNK_ + 1);

    // issue next group's staging loads (consumed at group end)
    if (layer) {
      const uint4* gp = (const uint4*)(region + ((size_t)(bg * 16 + sn_h) * T_ + (8 * gs + st_h)) * H_ + sq_h * 32);
#pragma unroll
      for (int i = 0; i < 4; ++i) sreg[i] = gp[i];
    } else if (tid < 128) {
      const float* xp = x + ((size_t)(bg * 16 + sn_x) * T_ + (8 * gs + st_x)) * IN_;
      xreg.x = pack2(xp[0], xp[1]); xreg.y = pack2(xp[2], xp[3]);
      xreg.z = pack2(xp[4], xp[5]); xreg.w = 0u;
    }

    // ---- 8 recurrence steps
#pragma unroll
    for (int s = 0; s < GRP_; ++s) {
      const int rp = s & 1, wp = rp ^ 1;
      const int ko = quad * 8;

      f16x8 hs[4];
#pragma unroll
      for (int kc = 0; kc < 4; ++kc)
        hs[kc] = *(const f16x8*)&hstate[rp][n16][kc * 32 + ko];

      f32x4 acc[4];
      if (layer) {
        f16x8 hi[4];
#pragma unroll
        for (int kc = 0; kc < 4; ++kc)
          hi[kc] = *(const f16x8*)&hbufL[s][n16][kc * 32 + ko];
#pragma unroll
        for (int j = 0; j < 4; ++j) {
          f32x4 aw = bias4[j];   // whh chain
          f32x4 ai = z4;         // wih chain (independent)
#pragma unroll
          for (int kc = 0; kc < 4; ++kc) {
            aw = __builtin_amdgcn_mfma_f32_16x16x32_f16(whh[j][kc], hs[kc], aw, 0, 0, 0);
            ai = __builtin_amdgcn_mfma_f32_16x16x32_f16(wih[j][kc], hi[kc], ai, 0, 0, 0);
          }
#pragma unroll
          for (int r = 0; r < 4; ++r) acc[j][r] = aw[r] + ai[r];
        }
      } else {
        f16x8 xi;
#pragma unroll
        for (int i = 0; i < 8; ++i) xi[i] = (_Float16)0.f;
        if (quad == 0) xi = *(const f16x8*)&xbuf[s][n16][0];
#pragma unroll
        for (int j = 0; j < 4; ++j) {
          f32x4 aw = bias4[j];
#pragma unroll
          for (int kc = 0; kc < 4; ++kc)
            aw = __builtin_amdgcn_mfma_f32_16x16x32_f16(whh[j][kc], hs[kc], aw, 0, 0, 0);
          f32x4 ai = __builtin_amdgcn_mfma_f32_16x16x32_f16(wx[j], xi, z4, 0, 0, 0);
#pragma unroll
          for (int r = 0; r < 4; ++r) acc[j][r] = aw[r] + ai[r];
        }
      }

      float hv4[4];
#pragma unroll
      for (int r = 0; r < 4; ++r) {
        float i_ = sigf_(acc[0][r]);
        float f_ = sigf_(acc[1][r]);
        float g_ = tanhf_(acc[2][r]);
        float o_ = sigf_(acc[3][r]);
        float cc = f_ * c4[r] + i_ * g_;
        c4[r] = cc;
        hv4[r] = o_ * tanhf_(cc);
      }
      unsigned int u0 = pack2(hv4[0], hv4[1]);
      unsigned int u1 = pack2(hv4[2], hv4[3]);
      d0[s] = u0; d1[s] = u1;
      uint2 hw; hw.x = u0; hw.y = u1;
      *(uint2*)&hstate[wp][n16][16 * wv + quad * 4] = hw;
      __syncthreads();
    }

    // deferred h-sequence stores
    if (layer < 2) {
#pragma unroll
      for (int s = 0; s < GRP_; ++s) {
        size_t off = ((size_t)(bg * 16 + n16) * T_ + (8 * g + s)) * H_ + 16 * wv + quad * 4;
        uint2 hw; hw.x = d0[s]; hw.y = d1[s];
        *(uint2*)(region + off) = hw;
      }
    }
    // staged regs -> LDS for next group
    if (layer) {
      uint4* lp = (uint4*)&hbufL[st_h][sn_h][sq_h * 32];
#pragma unroll
      for (int i = 0; i < 4; ++i) lp[i] = sreg[i];
    } else if (tid < 128) {
      *(uint4*)&xbuf[st_x][sn_x][0] = xreg;
    }
    __syncthreads();  // drains region stores (vmcnt) + publishes LDS

    // producer: publish once per chunk
    if (layer < 2 && ((8 * (g + 1)) % CHUNK_) == 0 && tid == 0) {
      __hip_atomic_store(flag_out, (unsigned int)((8 * (g + 1)) / CHUNK_),
                         __ATOMIC_RELEASE, __HIP_MEMORY_SCOPE_AGENT);
    }
  }
#undef WAIT_FOR

  if (layer == 2) {
    state_h[(bg * 16 + n16) * 64 + 8 * wv + 2 * quad]     = d0[GRP_ - 1];
    state_h[(bg * 16 + n16) * 64 + 8 * wv + 2 * quad + 1] = d1[GRP_ - 1];
  }
}

// ---------------------------------------------------------------------------
__global__ void head_kernel(const unsigned int* __restrict__ state_h,
                            const float* __restrict__ Wout,
                            const float* __restrict__ bout,
                            float* __restrict__ out)
{
  int b = threadIdx.x;  // 128 threads, 1 block
  float s = bout[0];
  for (int j = 0; j < 64; ++j) {
    unsigned int p = state_h[b * 64 + j];
    union { unsigned short u; _Float16 h; } lo, hi;
    lo.u = (unsigned short)(p & 0xffffu);
    hi.u = (unsigned short)(p >> 16);
    s += (float)lo.h * Wout[2 * j] + (float)hi.h * Wout[2 * j + 1];
  }
  out[b] = s;
}

// ---------------------------------------------------------------------------
extern "C" void kernel_launch(void* const* d_in, const int* in_sizes, int n_in,
                              void* d_out, int out_size, void* d_ws, size_t ws_size,
                              hipStream_t stream)
{
  const float* x = (const float*)d_in[0];
  const float* Wih[3] = {(const float*)d_in[1], (const float*)d_in[5], (const float*)d_in[9]};
  const float* Whh[3] = {(const float*)d_in[2], (const float*)d_in[6], (const float*)d_in[10]};
  const float* bih[3] = {(const float*)d_in[3], (const float*)d_in[7], (const float*)d_in[11]};
  const float* bhh[3] = {(const float*)d_in[4], (const float*)d_in[8], (const float*)d_in[12]};
  const float* Wout = (const float*)d_in[13];
  const float* bout = (const float*)d_in[14];
  float* out = (float*)d_out;

  char* ws = (char*)d_ws;
  size_t off = 0;
  unsigned short* region = (unsigned short*)(ws + off); off += (size_t)B_ * T_ * H_ * 2;  // 64 MiB
  unsigned int* state_h  = (unsigned int*)(ws + off);   off += (size_t)B_ * 64 * 4;
  off = (off + 255) & ~(size_t)255;
  unsigned int* flags    = (unsigned int*)(ws + off);   off += 16 * FLAG_STRIDE_ * 4;

  init_flags<<<4, 256, 0, stream>>>(flags);
  lstm_pipe<<<NBLK_, 512, 0, stream>>>(x,
      Wih[0], Whh[0], bih[0], bhh[0],
      Wih[1], Whh[1], bih[1], bhh[1],
      Wih[2], Whh[2], bih[2], bhh[2],
      region, state_h, flags);
  head_kernel<<<1, 128, 0, stream>>>(state_h, Wout, bout, out);
}

// Round 13
// 2430.035 us; speedup vs baseline: 1.3873x; 1.3873x over previous
//
#include <hip/hip_runtime.h>

#define B_ 128
#define T_ 2048
#define H_ 128
#define IN_ 6
#define GRP_ 8                  // steps per inner group
#define NGRP_ (T_ / GRP_)       // 256
#define CHUNK_ 32               // steps per flag chunk
#define NCHUNK_ (T_ / CHUNK_)   // 64
#define FLAG_STRIDE_ 64         // uints between flags (256B)
#define HS_ 144                 // LDS row stride in shorts
#define XGRING_ 3               // xg ring depth (chunks)
#define XGSLOT_ (CHUNK_ * 8192) // floats per ring slot: 32 steps * 512 gates * 16 batch

typedef _Float16 f16x8 __attribute__((ext_vector_type(8)));
typedef float    f32x4 __attribute__((ext_vector_type(4)));

__device__ __forceinline__ unsigned short f2h_u(float f) {
  union { _Float16 h; unsigned short u; } v; v.h = (_Float16)f; return v.u;
}
__device__ __forceinline__ unsigned int pack2(float a, float b) {
  return (unsigned int)f2h_u(a) | ((unsigned int)f2h_u(b) << 16);
}
__device__ __forceinline__ float sigf_(float x) {
  return __builtin_amdgcn_rcpf(1.0f + __expf(-x));
}
__device__ __forceinline__ float tanhf_(float x) {
  return 2.0f * __builtin_amdgcn_rcpf(1.0f + __expf(-2.0f * x)) - 1.0f;
}
__device__ __forceinline__ f16x8 load_w8(const float* __restrict__ p) {
  f16x8 r;
#pragma unroll
  for (int i = 0; i < 8; ++i) r[i] = (_Float16)p[i];
  return r;
}

__global__ void init_flags(unsigned int* flags) {
  flags[blockIdx.x * 256 + threadIdx.x] = 0u;  // grid 12 -> 3072 = 48 flags * 64
}

// ---------------------------------------------------------------------------
// 40 WGs: bid 0-23 = recurrence (layer=bid>>3, bg=bid&7);
//         bid 24-39 = input-GEMM producers (gl = 1 + (bid-24)>>3, bg).
// GEMM role: xg[chunk] = bias + Wih . h_in[chunk]  (fp32, 3-slot ring/bg).
// Rec role: per step only the whh MFMA chain, C-init = xg (prefetched 2 deep).
// Flags: fh 0-15 (h chunks ready), fx 16-31 (xg ready), fc 32-47 (xg consumed).
// R12 bug fixed here: h-row staging copies 16 uint4 (256B = 128 f16), not 8.
// ---------------------------------------------------------------------------
__global__ __launch_bounds__(512, 2)
void lstm_pipe(const float* __restrict__ x,
               const float* __restrict__ Wih0, const float* __restrict__ Whh0,
               const float* __restrict__ bih0, const float* __restrict__ bhh0,
               const float* __restrict__ Wih1, const float* __restrict__ Whh1,
               const float* __restrict__ bih1, const float* __restrict__ bhh1,
               const float* __restrict__ Wih2, const float* __restrict__ Whh2,
               const float* __restrict__ bih2, const float* __restrict__ bhh2,
               unsigned short* __restrict__ region,   // f16 [B][T][128]
               float* __restrict__ xg,                // fp32 rings [2][8][3][XGSLOT_]
               unsigned int* __restrict__ state_h,    // [B][64] f16x2
               unsigned int* __restrict__ flags)
{
  const int bid  = blockIdx.x;
  const int tid  = threadIdx.x;
  const int lane = tid & 63;
  const int wv   = tid >> 6;    // wave 0..7
  const int n16  = lane & 15;
  const int quad = lane >> 4;

  __shared__ unsigned short smem[32 * 16 * HS_];   // 147456 B
  __shared__ int s_have;

#define WAITP(ptr_, need_, have_)                                   \
  do {                                                              \
    if ((have_) < (need_)) {                                        \
      if (tid == 0) {                                               \
        int v = (int)__hip_atomic_load(ptr_, __ATOMIC_RELAXED,      \
                                       __HIP_MEMORY_SCOPE_AGENT);   \
        while (v < (need_)) {                                       \
          __builtin_amdgcn_s_sleep(2);                              \
          v = (int)__hip_atomic_load(ptr_, __ATOMIC_RELAXED,        \
                                     __HIP_MEMORY_SCOPE_AGENT);     \
        }                                                           \
        (void)__hip_atomic_load(ptr_, __ATOMIC_ACQUIRE,             \
                                __HIP_MEMORY_SCOPE_AGENT);          \
        s_have = v;                                                 \
      }                                                             \
      __syncthreads();                                              \
      (have_) = s_have;                                             \
    }                                                               \
  } while (0)

  if (bid >= 24) {
    // ======================= GEMM producer role ==========================
    const int gl = 1 + ((bid - 24) >> 3);  // produces xg for layer gl
    const int bg = (bid - 24) & 7;
    const float* Wih = (gl == 1) ? Wih1 : Wih2;
    const float* bih = (gl == 1) ? bih1 : bih2;
    const float* bhh = (gl == 1) ? bhh1 : bhh2;
    float* xgo = xg + (size_t)((gl - 1) * 8 + bg) * (XGRING_ * (size_t)XGSLOT_);
    unsigned int* fh_in  = &flags[((gl - 1) * 8 + bg) * FLAG_STRIDE_];
    unsigned int* fx_out = &flags[(16 + (gl - 1) * 8 + bg) * FLAG_STRIDE_];
    unsigned int* fc_in  = &flags[(32 + (gl - 1) * 8 + bg) * FLAG_STRIDE_];

    f16x8 wih[4][4];
#pragma unroll
    for (int j = 0; j < 4; ++j)
#pragma unroll
      for (int kc = 0; kc < 4; ++kc)
        wih[j][kc] = load_w8(Wih + (size_t)(j * 128 + 16 * wv + n16) * H_ + kc * 32 + quad * 8);
    f32x4 bias4[4];
#pragma unroll
    for (int j = 0; j < 4; ++j)
#pragma unroll
      for (int r = 0; r < 4; ++r) {
        int row = j * 128 + 16 * wv + quad * 4 + r;
        bias4[j][r] = bih[row] + bhh[row];
      }

    int have_h = 0, have_c = 0;
    const int tt = tid >> 4, bb = tid & 15;  // h-chunk staging map (1 thread/row)
    for (int k = 0; k < NCHUNK_; ++k) {
      WAITP(fh_in, k + 1, have_h);
      if (k >= XGRING_) WAITP(fc_in, k - (XGRING_ - 1), have_c);
      // stage h chunk [32][16][128] -> LDS : full row = 16 x uint4 (FIX)
      {
        const uint4* gp = (const uint4*)(region +
            ((size_t)(bg * 16 + bb) * T_ + (size_t)(CHUNK_ * k + tt)) * H_);
        uint4* lp = (uint4*)&smem[(tt * 16 + bb) * HS_];
#pragma unroll
        for (int i = 0; i < 16; ++i) lp[i] = gp[i];
      }
      __syncthreads();
      const int slot = k % XGRING_;
      for (int t = 0; t < CHUNK_; ++t) {
        f16x8 hi[4];
#pragma unroll
        for (int kc = 0; kc < 4; ++kc)
          hi[kc] = *(const f16x8*)&smem[(t * 16 + n16) * HS_ + kc * 32 + quad * 8];
        float* xp = xgo + (size_t)(slot * CHUNK_ + t) * 8192 + quad * 64 + n16 * 4;
#pragma unroll
        for (int j = 0; j < 4; ++j) {
          f32x4 a = bias4[j];
#pragma unroll
          for (int kc = 0; kc < 4; ++kc)
            a = __builtin_amdgcn_mfma_f32_16x16x32_f16(wih[j][kc], hi[kc], a, 0, 0, 0);
          *(f32x4*)(xp + (size_t)(8 * j + wv) * 256) = a;
        }
      }
      __syncthreads();  // drains stores (vmcnt) + protects LDS reuse
      if (tid == 0)
        __hip_atomic_store(fx_out, (unsigned int)(k + 1),
                           __ATOMIC_RELEASE, __HIP_MEMORY_SCOPE_AGENT);
    }
    return;
  }

  // ========================= Recurrence role =============================
  const int layer = bid >> 3;
  const int bg    = bid & 7;
  const float* Whh = (layer == 0) ? Whh0 : ((layer == 1) ? Whh1 : Whh2);

  unsigned short* hstate = smem;                  // [2][16][HS_]
  unsigned short* xb = smem + 2 * 16 * HS_;       // [8][16][8] (layer 0 only)

  f16x8 whh[4][4];
#pragma unroll
  for (int j = 0; j < 4; ++j)
#pragma unroll
    for (int kc = 0; kc < 4; ++kc)
      whh[j][kc] = load_w8(Whh + (size_t)(j * 128 + 16 * wv + n16) * H_ + kc * 32 + quad * 8);

  for (int i = tid; i < (2 * 16 * HS_) / 2; i += 512) ((unsigned int*)smem)[i] = 0u;

  f32x4 c4 = {0.f, 0.f, 0.f, 0.f};
  unsigned int d0[GRP_], d1[GRP_];
  unsigned int* fh_out = (layer < 2) ? &flags[(layer * 8 + bg) * FLAG_STRIDE_] : nullptr;
  unsigned int* fx_in  = (layer > 0) ? &flags[(16 + (layer - 1) * 8 + bg) * FLAG_STRIDE_] : nullptr;
  unsigned int* fc_out = (layer > 0) ? &flags[(32 + (layer - 1) * 8 + bg) * FLAG_STRIDE_] : nullptr;

  if (layer == 0) {
    // ------------------------- layer 0 ---------------------------------
    const float* Wih = Wih0;
    f32x4 bias4[4];
#pragma unroll
    for (int j = 0; j < 4; ++j)
#pragma unroll
      for (int r = 0; r < 4; ++r) {
        int row = j * 128 + 16 * wv + quad * 4 + r;
        bias4[j][r] = bih0[row] + bhh0[row];
      }
    f16x8 wx[4];
#pragma unroll
    for (int j = 0; j < 4; ++j)
#pragma unroll
      for (int i = 0; i < 8; ++i) wx[j][i] = (_Float16)0.f;
    if (quad == 0) {
#pragma unroll
      for (int j = 0; j < 4; ++j) {
        const float* p = Wih + (size_t)(j * 128 + 16 * wv + n16) * IN_;
#pragma unroll
        for (int i = 0; i < IN_; ++i) wx[j][i] = (_Float16)p[i];
      }
    }
    const f32x4 z4 = {0.f, 0.f, 0.f, 0.f};
    const int sn_x = tid >> 3, st_x = tid & 7;
    uint4 xreg = {0u, 0u, 0u, 0u};
    __syncthreads();
    if (tid < 128) {
      const float* xp = x + ((size_t)(bg * 16 + sn_x) * T_ + st_x) * IN_;
      xreg.x = pack2(xp[0], xp[1]); xreg.y = pack2(xp[2], xp[3]);
      xreg.z = pack2(xp[4], xp[5]); xreg.w = 0u;
      *(uint4*)&xb[(st_x * 16 + sn_x) * 8] = xreg;
    }
    __syncthreads();

    for (int g = 0; g < NGRP_; ++g) {
      int gs = (g + 1 < NGRP_) ? (g + 1) : g;
      if (tid < 128) {
        const float* xp = x + ((size_t)(bg * 16 + sn_x) * T_ + (8 * gs + st_x)) * IN_;
        xreg.x = pack2(xp[0], xp[1]); xreg.y = pack2(xp[2], xp[3]);
        xreg.z = pack2(xp[4], xp[5]); xreg.w = 0u;
      }
#pragma unroll
      for (int s = 0; s < GRP_; ++s) {
        const int rp = s & 1, wp = rp ^ 1;
        f16x8 hs[4];
#pragma unroll
        for (int kc = 0; kc < 4; ++kc)
          hs[kc] = *(const f16x8*)&hstate[(rp * 16 + n16) * HS_ + kc * 32 + quad * 8];
        f16x8 xi;
#pragma unroll
        for (int i = 0; i < 8; ++i) xi[i] = (_Float16)0.f;
        if (quad == 0) xi = *(const f16x8*)&xb[(s * 16 + n16) * 8];
        f32x4 acc[4];
#pragma unroll
        for (int j = 0; j < 4; ++j) {
          f32x4 aw = bias4[j];
#pragma unroll
          for (int kc = 0; kc < 4; ++kc)
            aw = __builtin_amdgcn_mfma_f32_16x16x32_f16(whh[j][kc], hs[kc], aw, 0, 0, 0);
          f32x4 ai = __builtin_amdgcn_mfma_f32_16x16x32_f16(wx[j], xi, z4, 0, 0, 0);
#pragma unroll
          for (int r = 0; r < 4; ++r) acc[j][r] = aw[r] + ai[r];
        }
        float hv4[4];
#pragma unroll
        for (int r = 0; r < 4; ++r) {
          float i_ = sigf_(acc[0][r]);
          float f_ = sigf_(acc[1][r]);
          float g_ = tanhf_(acc[2][r]);
          float o_ = sigf_(acc[3][r]);
          float cc = f_ * c4[r] + i_ * g_;
          c4[r] = cc;
          hv4[r] = o_ * tanhf_(cc);
        }
        unsigned int u0 = pack2(hv4[0], hv4[1]);
        unsigned int u1 = pack2(hv4[2], hv4[3]);
        d0[s] = u0; d1[s] = u1;
        uint2 hw; hw.x = u0; hw.y = u1;
        *(uint2*)&hstate[(wp * 16 + n16) * HS_ + 16 * wv + quad * 4] = hw;
        __syncthreads();
      }
      // deferred h stores + next-group x staging
#pragma unroll
      for (int s = 0; s < GRP_; ++s) {
        size_t off = ((size_t)(bg * 16 + n16) * T_ + (8 * g + s)) * H_ + 16 * wv + quad * 4;
        uint2 hw; hw.x = d0[s]; hw.y = d1[s];
        *(uint2*)(region + off) = hw;
      }
      if (tid < 128) *(uint4*)&xb[(st_x * 16 + sn_x) * 8] = xreg;
      __syncthreads();  // drains region stores + publishes xb
      if (((8 * (g + 1)) % CHUNK_) == 0 && tid == 0)
        __hip_atomic_store(fh_out, (unsigned int)((8 * (g + 1)) / CHUNK_),
                           __ATOMIC_RELEASE, __HIP_MEMORY_SCOPE_AGENT);
    }
  } else {
    // ----------------------- layers 1 and 2 ----------------------------
    const float* xgi = xg + (size_t)((layer - 1) * 8 + bg) * (XGRING_ * (size_t)XGSLOT_);
    f32x4 xr[2][4];
    auto load_xg = [&](int t, int buf) {
      int slot = (t >> 5) % XGRING_;
      const float* p = xgi + (size_t)(slot * CHUNK_ + (t & 31)) * 8192
                       + (size_t)wv * 256 + quad * 64 + n16 * 4;
      xr[buf][0] = *(const f32x4*)(p);
      xr[buf][1] = *(const f32x4*)(p + 2048);
      xr[buf][2] = *(const f32x4*)(p + 4096);
      xr[buf][3] = *(const f32x4*)(p + 6144);
    };
    int have_x = 0;
    __syncthreads();  // hstate zero visible

    for (int g = 0; g < NGRP_; ++g) {
      if ((g & 3) == 0) {
        int c = g >> 2;
        WAITP(fx_in, c + 1, have_x);
        load_xg(32 * c, 0);
        load_xg(32 * c + 1, 1);
      }
#pragma unroll
      for (int s = 0; s < GRP_; ++s) {
        const int t = 8 * g + s;
        const int rp = s & 1, wp = rp ^ 1;
        f16x8 hs[4];
#pragma unroll
        for (int kc = 0; kc < 4; ++kc)
          hs[kc] = *(const f16x8*)&hstate[(rp * 16 + n16) * HS_ + kc * 32 + quad * 8];
        f32x4 ci[4];
#pragma unroll
        for (int j = 0; j < 4; ++j) ci[j] = xr[s & 1][j];
        if (!(((g & 3) == 3) && s >= 6)) load_xg(t + 2, s & 1);
        f32x4 acc[4];
#pragma unroll
        for (int j = 0; j < 4; ++j) {
          f32x4 aw = ci[j];
#pragma unroll
          for (int kc = 0; kc < 4; ++kc)
            aw = __builtin_amdgcn_mfma_f32_16x16x32_f16(whh[j][kc], hs[kc], aw, 0, 0, 0);
          acc[j] = aw;
        }
        float hv4[4];
#pragma unroll
        for (int r = 0; r < 4; ++r) {
          float i_ = sigf_(acc[0][r]);
          float f_ = sigf_(acc[1][r]);
          float g_ = tanhf_(acc[2][r]);
          float o_ = sigf_(acc[3][r]);
          float cc = f_ * c4[r] + i_ * g_;
          c4[r] = cc;
          hv4[r] = o_ * tanhf_(cc);
        }
        unsigned int u0 = pack2(hv4[0], hv4[1]);
        unsigned int u1 = pack2(hv4[2], hv4[3]);
        d0[s] = u0; d1[s] = u1;
        uint2 hw; hw.x = u0; hw.y = u1;
        *(uint2*)&hstate[(wp * 16 + n16) * HS_ + 16 * wv + quad * 4] = hw;
        __syncthreads();
      }
      if (layer == 1) {
#pragma unroll
        for (int s = 0; s < GRP_; ++s) {
          size_t off = ((size_t)(bg * 16 + n16) * T_ + (8 * g + s)) * H_ + 16 * wv + quad * 4;
          uint2 hw; hw.x = d0[s]; hw.y = d1[s];
          *(uint2*)(region + off) = hw;
        }
        __syncthreads();  // drain h stores before fh publish
      }
      if (((g & 3) == 3) && tid == 0) {
        unsigned int cdone = (unsigned int)((g >> 2) + 1);
        if (layer == 1)
          __hip_atomic_store(fh_out, cdone, __ATOMIC_RELEASE, __HIP_MEMORY_SCOPE_AGENT);
        __hip_atomic_store(fc_out, cdone, __ATOMIC_RELEASE, __HIP_MEMORY_SCOPE_AGENT);
      }
    }
    if (layer == 2) {
      state_h[(bg * 16 + n16) * 64 + 8 * wv + 2 * quad]     = d0[GRP_ - 1];
      state_h[(bg * 16 + n16) * 64 + 8 * wv + 2 * quad + 1] = d1[GRP_ - 1];
    }
  }
#undef WAITP
}

// ---------------------------------------------------------------------------
__global__ void head_kernel(const unsigned int* __restrict__ state_h,
                            const float* __restrict__ Wout,
                            const float* __restrict__ bout,
                            float* __restrict__ out)
{
  int b = threadIdx.x;  // 128 threads, 1 block
  float s = bout[0];
  for (int j = 0; j < 64; ++j) {
    unsigned int p = state_h[b * 64 + j];
    union { unsigned short u; _Float16 h; } lo, hi;
    lo.u = (unsigned short)(p & 0xffffu);
    hi.u = (unsigned short)(p >> 16);
    s += (float)lo.h * Wout[2 * j] + (float)hi.h * Wout[2 * j + 1];
  }
  out[b] = s;
}

// ---------------------------------------------------------------------------
extern "C" void kernel_launch(void* const* d_in, const int* in_sizes, int n_in,
                              void* d_out, int out_size, void* d_ws, size_t ws_size,
                              hipStream_t stream)
{
  const float* x = (const float*)d_in[0];
  const float* Wih[3] = {(const float*)d_in[1], (const float*)d_in[5], (const float*)d_in[9]};
  const float* Whh[3] = {(const float*)d_in[2], (const float*)d_in[6], (const float*)d_in[10]};
  const float* bih[3] = {(const float*)d_in[3], (const float*)d_in[7], (const float*)d_in[11]};
  const float* bhh[3] = {(const float*)d_in[4], (const float*)d_in[8], (const float*)d_in[12]};
  const float* Wout = (const float*)d_in[13];
  const float* bout = (const float*)d_in[14];
  float* out = (float*)d_out;

  char* ws = (char*)d_ws;
  size_t off = 0;
  unsigned short* region = (unsigned short*)(ws + off); off += (size_t)B_ * T_ * H_ * 2;   // 64 MiB
  float* xg = (float*)(ws + off);                       off += (size_t)16 * XGRING_ * XGSLOT_ * 4;  // 48 MiB
  unsigned int* state_h  = (unsigned int*)(ws + off);   off += (size_t)B_ * 64 * 4;
  off = (off + 255) & ~(size_t)255;
  unsigned int* flags    = (unsigned int*)(ws + off);   off += 48 * FLAG_STRIDE_ * 4;

  init_flags<<<12, 256, 0, stream>>>(flags);
  lstm_pipe<<<40, 512, 0, stream>>>(x,
      Wih[0], Whh[0], bih[0], bhh[0],
      Wih[1], Whh[1], bih[1], bhh[1],
      Wih[2], Whh[2], bih[2], bhh[2],
      region, xg, state_h, flags);
  head_kernel<<<1, 128, 0, stream>>>(state_h, Wout, bout, out);
}